// Round 4
// baseline (377.554 us; speedup 1.0000x reference)
//
#include <hip/hip_runtime.h>

// Problem: inputs (B=32, L=720, C=862) f32. Output (T=4, B, C, L) f32 spikes.
// x is broadcast across T => element-wise 4-step LIF. Memory-bound:
// 79.4 MB read + 317.8 MB write => ~63 us kernel roofline.
//
// R4: A/B vs R3 — ONLY change: plain stores instead of
// __builtin_nontemporal_store. Harness fill shows plain full-line writes
// run 6.4 TB/s with FETCH~0 (no RFO); suspect `nt` path caps at ~2.7 TB/s.

#define B_DIM 32
#define L_DIM 720
#define C_DIM 862
#define T_STEPS 4
#define TC 16
#define SL 724   // LDS l-stride per c row (floats): %4==0 (b128), %8==4 (banks)

typedef float v2f __attribute__((ext_vector_type(2)));
typedef float v4f __attribute__((ext_vector_type(4)));

__global__ __launch_bounds__(256)
void lif_repeat_encoder(const float* __restrict__ in, float* __restrict__ out) {
    __shared__ float sm[TC * SL];   // 46,336 B

    const int b   = blockIdx.y;
    const int c0  = blockIdx.x * TC;
    const int tid = threadIdx.x;

    const float* __restrict__ inb = in + (size_t)b * (L_DIM * C_DIM);

    // ---- Load phase: rows l, 2 consecutive c per lane (float2, 8B-aligned).
    {
        const int cl2 = (tid & 7) << 1;   // c_local: 0,2,...,14
        const int c   = c0 + cl2;
        const int r0  = tid >> 3;         // 0..31
        if (c < C_DIM) {
            for (int base = 0; base < L_DIM; base += 128) {
                v2f v[4];
#pragma unroll
                for (int u = 0; u < 4; ++u) {
                    const int r = base + r0 + 32 * u;
                    if (r < L_DIM)
                        v[u] = *(const v2f*)(inb + (size_t)r * C_DIM + c);
                }
#pragma unroll
                for (int u = 0; u < 4; ++u) {
                    const int r = base + r0 + 32 * u;
                    if (r < L_DIM) {
                        sm[cl2 * SL + r]       = v[u].x;
                        sm[(cl2 + 1) * SL + r] = v[u].y;
                    }
                }
            }
        }
    }
    __syncthreads();

    // ---- Store phase: wave w handles c_local = 4w..4w+3; per (c,t) the wave
    // writes the FULL 720-float row in 3 float4 rounds (64+64+52 lanes).
    const int wave = tid >> 6;   // 0..3
    const int lane = tid & 63;
    const size_t plane = (size_t)B_DIM * C_DIM * L_DIM;

#pragma unroll
    for (int q = 0; q < 4; ++q) {
        const int cl = wave * 4 + q;
        const int c  = c0 + cl;
        if (c >= C_DIM) continue;

        const size_t rowbase = ((size_t)b * C_DIM + c) * L_DIM;

#pragma unroll
        for (int round = 0; round < 3; ++round) {
            const int j = lane + 64 * round;       // float4 index within row
            if (j >= L_DIM / 4) break;             // 180 float4 per row

            const v4f x = *(const v4f*)(sm + cl * SL + 4 * j);

            // LIF: v += (x - v)*0.5 ; s = (v>=1) ; v = s ? 0 : v   (exact ref)
            float sx[T_STEPS], sy[T_STEPS], sz[T_STEPS], sw[T_STEPS];
            float v0 = 0.f, v1 = 0.f, v2 = 0.f, v3 = 0.f;
#pragma unroll
            for (int t = 0; t < T_STEPS; ++t) {
                v0 += (x.x - v0) * 0.5f;
                v1 += (x.y - v1) * 0.5f;
                v2 += (x.z - v2) * 0.5f;
                v3 += (x.w - v3) * 0.5f;
                sx[t] = (v0 >= 1.0f) ? 1.0f : 0.0f;
                sy[t] = (v1 >= 1.0f) ? 1.0f : 0.0f;
                sz[t] = (v2 >= 1.0f) ? 1.0f : 0.0f;
                sw[t] = (v3 >= 1.0f) ? 1.0f : 0.0f;
                v0 = (v0 >= 1.0f) ? 0.0f : v0;
                v1 = (v1 >= 1.0f) ? 0.0f : v1;
                v2 = (v2 >= 1.0f) ? 0.0f : v2;
                v3 = (v3 >= 1.0f) ? 0.0f : v3;
            }

#pragma unroll
            for (int t = 0; t < T_STEPS; ++t) {
                v4f o;
                o.x = sx[t]; o.y = sy[t]; o.z = sz[t]; o.w = sw[t];
                *(v4f*)(out + (size_t)t * plane + rowbase + 4 * j) = o;
            }
        }
    }
}

extern "C" void kernel_launch(void* const* d_in, const int* in_sizes, int n_in,
                              void* d_out, int out_size, void* d_ws, size_t ws_size,
                              hipStream_t stream) {
    const float* in = (const float*)d_in[0];
    float* out = (float*)d_out;

    dim3 block(256, 1, 1);
    dim3 grid((C_DIM + TC - 1) / TC,   // 54
              B_DIM,                   // 32
              1);

    lif_repeat_encoder<<<grid, block, 0, stream>>>(in, out);
}

// Round 5
// 374.894 us; speedup vs baseline: 1.0071x; 1.0071x over previous
//
#include <hip/hip_runtime.h>

// Problem: inputs (B=32, L=720, C=862) f32. Output (T=4, B, C, L) f32 spikes.
// x is broadcast across T => element-wise 4-step LIF. Memory-bound:
// 79.4 MB read + 317.8 MB write => ~63 us kernel roofline.
//
// R5: fill-like write phase. Spikes computed at load time, bit-packed
// (4 t-bits/byte) into 11.6 KB LDS [c][l]. Store phase iterates t OUTERMOST:
// each wave writes 4 adjacent c-rows of one plane back-to-back (11.5 KB
// sequential per wave per plane) -- one write stream per wave, like the
// 6.4 TB/s harness fill, instead of per-instruction 4-plane hopping.
// Occupancy 3 -> 8 blocks/CU (LDS 46 KB -> 11.6 KB).

#define B_DIM 32
#define L_DIM 720
#define C_DIM 862
#define T_STEPS 4
#define TC 16
#define SLB 724   // spike-LDS l-stride in BYTES per c-row (%4==0 for b32 reads)

typedef float v2f __attribute__((ext_vector_type(2)));
typedef float v4f __attribute__((ext_vector_type(4)));

__device__ __forceinline__ unsigned lif_spike_byte(float x) {
    // Exact reference semantics: v += (x - v)*0.5 ; s = (v>=1) ; v = s ? 0 : v
    float v = 0.0f;
    unsigned b = 0;
#pragma unroll
    for (int t = 0; t < T_STEPS; ++t) {
        v += (x - v) * 0.5f;
        if (v >= 1.0f) { b |= (1u << t); v = 0.0f; }
    }
    return b;
}

__global__ __launch_bounds__(256)
void lif_repeat_encoder(const float* __restrict__ in, float* __restrict__ out) {
    __shared__ unsigned char sl[TC * SLB];   // 11,584 B, sl[c][l] spike bytes

    const int b   = blockIdx.y;
    const int c0  = blockIdx.x * TC;
    const int tid = threadIdx.x;

    const float* __restrict__ inb = in + (size_t)b * (L_DIM * C_DIM);

    // ---- Load + compute phase: lane reads float2 (2 c), emits 2 spike bytes.
    {
        const int cl2 = (tid & 7) << 1;   // c_local: 0,2,...,14
        const int c   = c0 + cl2;
        const int r0  = tid >> 3;         // 0..31
        if (c < C_DIM) {                  // tail tile: cl2=14 lane inactive
            for (int base = 0; base < L_DIM; base += 128) {
                v2f v[4];
#pragma unroll
                for (int u = 0; u < 4; ++u) {
                    const int r = base + r0 + 32 * u;
                    if (r < L_DIM)
                        v[u] = *(const v2f*)(inb + (size_t)r * C_DIM + c);
                }
#pragma unroll
                for (int u = 0; u < 4; ++u) {
                    const int r = base + r0 + 32 * u;
                    if (r < L_DIM) {
                        sl[cl2 * SLB + r]       = (unsigned char)lif_spike_byte(v[u].x);
                        sl[(cl2 + 1) * SLB + r] = (unsigned char)lif_spike_byte(v[u].y);
                    }
                }
            }
        }
    }
    __syncthreads();

    // ---- Preload spike dwords: wave w owns c-rows 4w..4w+3; per (row, round)
    // one b32 = spikes for l = 4j..4j+3 (lane-consecutive addresses: no conflict).
    const int wave = tid >> 6;   // 0..3
    const int lane = tid & 63;

    unsigned sp[4][3];
#pragma unroll
    for (int q = 0; q < 4; ++q) {
#pragma unroll
        for (int round = 0; round < 3; ++round) {
            const int j = lane + 64 * round;       // float4 index in row, <180
            const int cl = 4 * wave + q;
            sp[q][round] = (j < L_DIM / 4)
                ? *(const unsigned*)(sl + cl * SLB + 4 * j) : 0u;
        }
    }

    // ---- Store phase: t OUTERMOST. Per t, wave writes its 4 adjacent c-rows
    // sequentially (4 x 2880 B contiguous) -- one stream per wave per plane.
    const size_t plane = (size_t)B_DIM * C_DIM * L_DIM;

#pragma unroll
    for (int t = 0; t < T_STEPS; ++t) {
#pragma unroll
        for (int q = 0; q < 4; ++q) {
            const int c = c0 + 4 * wave + q;
            if (c >= C_DIM) continue;
            float* dst = out + (size_t)t * plane + ((size_t)b * C_DIM + c) * L_DIM;
#pragma unroll
            for (int round = 0; round < 3; ++round) {
                const int j = lane + 64 * round;
                if (j >= L_DIM / 4) break;         // round 2: lanes 0..51
                const unsigned y = (sp[q][round] >> t) & 0x01010101u;
                v4f o;
                o.x = (float)(y & 1u);
                o.y = (float)((y >> 8) & 1u);
                o.z = (float)((y >> 16) & 1u);
                o.w = (float)((y >> 24) & 1u);
                *(v4f*)(dst + 4 * j) = o;
            }
        }
    }
}

extern "C" void kernel_launch(void* const* d_in, const int* in_sizes, int n_in,
                              void* d_out, int out_size, void* d_ws, size_t ws_size,
                              hipStream_t stream) {
    const float* in = (const float*)d_in[0];
    float* out = (float*)d_out;

    dim3 block(256, 1, 1);
    dim3 grid((C_DIM + TC - 1) / TC,   // 54
              B_DIM,                   // 32
              1);

    lif_repeat_encoder<<<grid, block, 0, stream>>>(in, out);
}

// Round 6
// 370.616 us; speedup vs baseline: 1.0187x; 1.0115x over previous
//
#include <hip/hip_runtime.h>

// Problem: inputs (B=32, L=720, C=862) f32. Output (T=4, B, C, L) f32 spikes.
// x is broadcast across T => element-wise 4-step LIF. Memory-bound:
// 79.4 MB read + 317.8 MB write => ~63 us kernel roofline.
//
// R6: read-side restructure. TC=32 (128 B burst per input row, was 64 B ~2x
// misalign-amplified). Each thread owns 4 consecutive l-rows per column and
// packs 4 spike bytes into ONE ds_write_b32 (no byte-granular LDS writes;
// exactly 2-way bank aliasing = free). Store: t-outermost, wave's 8 c-rows
// linearized as one contiguous 23 KB region per plane, spikes preloaded in
// 23 VGPRs, branch-free fast path for full tiles. LDS 23.2 KB -> 6 blk/CU.

#define B_DIM 32
#define L_DIM 720
#define C_DIM 862
#define T_STEPS 4
#define TC 32
#define SLB 724   // bytes per c-row in LDS: %4==0 (dword), /4%32=21 (odd spread)

typedef float v2f __attribute__((ext_vector_type(2)));
typedef float v4f __attribute__((ext_vector_type(4)));

__device__ __forceinline__ unsigned lif_spike_byte(float x) {
    // Exact reference semantics: v += (x - v)*0.5 ; s = (v>=1) ; v = s ? 0 : v
    float v = 0.0f;
    unsigned b = 0;
#pragma unroll
    for (int t = 0; t < T_STEPS; ++t) {
        v += (x - v) * 0.5f;
        if (v >= 1.0f) { b |= (1u << t); v = 0.0f; }
    }
    return b;
}

__global__ __launch_bounds__(256)
void lif_repeat_encoder(const float* __restrict__ in, float* __restrict__ out) {
    __shared__ unsigned char sl[TC * SLB];   // 23,168 B; sl[c_local][l] spike bytes

    const int b   = blockIdx.y;
    const int c0  = blockIdx.x * TC;
    const int tid = threadIdx.x;

    const float* __restrict__ inb = in + (size_t)b * (L_DIM * C_DIM);

    // ---- Load + compute: thread owns c-pair (2*c2, 2*c2+1) and 4 consecutive
    // rows per pass. One instruction = 16 lanes x 8 B = 128 B contiguous per
    // row. Packs 4 rows' spikes into one dword per column -> ds_write_b32.
    {
        const int c2 = tid & 15;          // c-pair index 0..15
        const int rg = tid >> 4;          // row-group 0..15
        const int cl = 2 * c2;            // c_local
        const int c  = c0 + cl;
        const bool cok = (c + 1) < C_DIM; // tail tile: c2=15 inactive

        for (int P = 0; P < 12; ++P) {
            const int rbase = 64 * P + 4 * rg;    // multiple of 4
            if (cok && rbase < L_DIM) {
                v2f x[4];
#pragma unroll
                for (int u = 0; u < 4; ++u)
                    x[u] = *(const v2f*)(inb + (size_t)(rbase + u) * C_DIM + c);
                unsigned p0 = 0, p1 = 0;
#pragma unroll
                for (int u = 0; u < 4; ++u) {
                    p0 |= lif_spike_byte(x[u].x) << (8 * u);
                    p1 |= lif_spike_byte(x[u].y) << (8 * u);
                }
                *(unsigned*)(sl + cl * SLB + rbase)       = p0;
                *(unsigned*)(sl + (cl + 1) * SLB + rbase) = p1;
            }
        }
    }
    __syncthreads();

    // ---- Preload: wave w owns c-rows 8w..8w+7 = 5760 floats = 1440 float4
    // slots, linearized. Slot s -> cl = s/180, l = 4*(s%180).
    const int wave = tid >> 6;
    const int lane = tid & 63;
    const int row0 = 8 * wave;

    unsigned sp[23];
#pragma unroll
    for (int k = 0; k < 23; ++k) {
        const int s = lane + 64 * k;
        sp[k] = (s < 1440)
            ? *(const unsigned*)(sl + (row0 + s / 180) * SLB + 4 * (s % 180))
            : 0u;
    }

    // ---- Store: t OUTERMOST; wave streams its contiguous 23,040 B region of
    // each plane in 23 v4f rounds. Fast path (26/27 tiles): no predicates.
    const size_t plane = (size_t)B_DIM * C_DIM * L_DIM;
    const bool full = (c0 + TC) <= C_DIM;
    float* const dst0 = out + ((size_t)b * C_DIM + c0 + row0) * L_DIM;

#pragma unroll
    for (int t = 0; t < T_STEPS; ++t) {
        float* const dstt = dst0 + (size_t)t * plane;
        if (full) {
#pragma unroll
            for (int k = 0; k < 23; ++k) {
                const int s = lane + 64 * k;
                if (s >= 1440) break;              // only k=22 partial
                const unsigned y = (sp[k] >> t) & 0x01010101u;
                v4f o;
                o.x = (float)(y & 1u);
                o.y = (float)((y >> 8) & 1u);
                o.z = (float)((y >> 16) & 1u);
                o.w = (float)((y >> 24) & 1u);
                *(v4f*)(dstt + 4 * (size_t)s) = o;
            }
        } else {
#pragma unroll
            for (int k = 0; k < 23; ++k) {
                const int s = lane + 64 * k;
                if (s >= 1440) break;
                const int cl = s / 180;
                if (c0 + row0 + cl >= C_DIM) continue;
                const unsigned y = (sp[k] >> t) & 0x01010101u;
                v4f o;
                o.x = (float)(y & 1u);
                o.y = (float)((y >> 8) & 1u);
                o.z = (float)((y >> 16) & 1u);
                o.w = (float)((y >> 24) & 1u);
                *(v4f*)(dstt + 4 * (size_t)s) = o;
            }
        }
    }
}

extern "C" void kernel_launch(void* const* d_in, const int* in_sizes, int n_in,
                              void* d_out, int out_size, void* d_ws, size_t ws_size,
                              hipStream_t stream) {
    const float* in = (const float*)d_in[0];
    float* out = (float*)d_out;

    dim3 block(256, 1, 1);
    dim3 grid((C_DIM + TC - 1) / TC,   // 27
              B_DIM,                   // 32
              1);

    lif_repeat_encoder<<<grid, block, 0, stream>>>(in, out);
}